// Round 7
// baseline (1287.735 us; speedup 1.0000x reference)
//
#include <hip/hip_runtime.h>
#include <stdint.h>

#define HOR 128
#define NPATH 4096
#define BATCH 8
#define DM 512
#define H 64
#define BN (BATCH*NPATH)
#define WSTRIDE 516   // j-strip stride in LDS: strip bases hit disjoint bank quads
#define TSTRIDE 132   // padded transpose-row stride

// ---------------- threefry2x32 (JAX-exact) ----------------
__device__ __forceinline__ uint32_t rotl32(uint32_t x, int r) {
  return (x << r) | (x >> (32 - r));
}

__device__ __forceinline__ void tf2x32(uint32_t k0, uint32_t k1,
                                       uint32_t& x0, uint32_t& x1) {
  uint32_t k2 = k0 ^ k1 ^ 0x1BD11BDAu;
  x0 += k0; x1 += k1;
#define TFR4(a,b,c,d) \
  x0 += x1; x1 = rotl32(x1,a); x1 ^= x0; \
  x0 += x1; x1 = rotl32(x1,b); x1 ^= x0; \
  x0 += x1; x1 = rotl32(x1,c); x1 ^= x0; \
  x0 += x1; x1 = rotl32(x1,d); x1 ^= x0;
  TFR4(13,15,26,6)  x0 += k1; x1 += k2 + 1u;
  TFR4(17,29,16,24) x0 += k2; x1 += k0 + 2u;
  TFR4(13,15,26,6)  x0 += k0; x1 += k1 + 3u;
  TFR4(17,29,16,24) x0 += k1; x1 += k2 + 4u;
  TFR4(13,15,26,6)  x0 += k2; x1 += k0 + 5u;
#undef TFR4
}

// ---------------- math helpers ----------------
__device__ __forceinline__ float rcpf(float x) { return __builtin_amdgcn_rcpf(x); }
__device__ __forceinline__ float siluf(float x) {
  return x * rcpf(1.0f + __expf(-x));
}
__device__ __forceinline__ float softplusf(float x) {
  return fmaxf(x, 0.0f) + log1pf(__expf(-fabsf(x)));
}

__device__ __forceinline__ float bits_to_normal(uint32_t bits) {
  uint32_t fb = (bits >> 9) | 0x3F800000u;
  float f = __uint_as_float(fb) - 1.0f;
  float u = fmaf(f, 2.0f, -0.99999994f);
  u = fmaxf(u, -0.99999994f);
  float w = -log1pf(-u * u);
  float p;
  if (w < 5.0f) {
    w = w - 2.5f;
    p = 2.81022636e-08f;
    p = fmaf(p, w, 3.43273939e-07f);
    p = fmaf(p, w, -3.5233877e-06f);
    p = fmaf(p, w, -4.39150654e-06f);
    p = fmaf(p, w, 0.00021858087f);
    p = fmaf(p, w, -0.00125372503f);
    p = fmaf(p, w, -0.00417768164f);
    p = fmaf(p, w, 0.246640727f);
    p = fmaf(p, w, 1.50140941f);
  } else {
    w = sqrtf(w) - 3.0f;
    p = -0.000200214257f;
    p = fmaf(p, w, 0.000100950558f);
    p = fmaf(p, w, 0.00134934322f);
    p = fmaf(p, w, -0.00367342844f);
    p = fmaf(p, w, 0.00573950773f);
    p = fmaf(p, w, -0.0076224613f);
    p = fmaf(p, w, 0.00943887047f);
    p = fmaf(p, w, 1.00167406f);
    p = fmaf(p, w, 2.83297682f);
  }
  return 1.41421356237f * (p * u);
}

// ws layout (floats): [0,512) base_f1[b][j], [512,1024) base_g1[b][j],
// (u32 view) [1024,1152) keyA[t], [1152,1280) keyB[t]

__global__ void k_pre(const float* __restrict__ h_t,
                      const float* __restrict__ W_f1, const float* __restrict__ b_f1,
                      const float* __restrict__ W_g1, const float* __restrict__ b_g1,
                      const float* __restrict__ W_mu, const float* __restrict__ b_mu,
                      const float* __restrict__ W_sig, const float* __restrict__ b_sig,
                      float* __restrict__ out, float* __restrict__ ws) {
  int j = threadIdx.x;           // 0..63
  int b = blockIdx.x;
  if (b == 8) {
    uint32_t* keyA = (uint32_t*)ws + 1024;
    uint32_t* keyB = (uint32_t*)ws + 1152;
    for (int t = j; t < HOR; t += 64) {
      uint32_t x0 = 0u, x1 = (uint32_t)t;
      tf2x32(0u, 42u, x0, x1);
      keyA[t] = x0; keyB[t] = x1;
    }
    return;
  }
  const float* h = h_t + b * DM;
  float accF = b_f1[j], accG = b_g1[j];
  float pm = 0.0f, ps = 0.0f;
  #pragma unroll 4
  for (int d = 0; d < DM; ++d) {
    float hv = h[d];
    accF = fmaf(hv, W_f1[d * H + j], accF);
    accG = fmaf(hv, W_g1[d * H + j], accG);
  }
  ws[b * H + j] = accF;
  ws[512 + b * H + j] = accG;
  for (int d = j; d < DM; d += 64) {
    pm = fmaf(h[d], W_mu[d], pm);
    ps = fmaf(h[d], W_sig[d], ps);
  }
  #pragma unroll
  for (int off = 32; off > 0; off >>= 1) {
    pm += __shfl_down(pm, off);
    ps += __shfl_down(ps, off);
  }
  if (j == 0) {
    out[BN * HOR + b] = pm + b_mu[0];
    out[BN * HOR + 8 + b] = softplusf(ps + b_sig[0]) + 1e-6f;
  }
}

// 8 lanes per row; 32 rows per 256-thread block; 1024 blocks -> 4096 waves
// = 4 waves/SIMD (R6's 2-row pairing capped it at 2/SIMD = the 72% VALU
// ceiling). Loop structure per R6 post-mortem: peeled bb=0 + REAL bb-loop
// (unroll 1) keeps in-flight LDS loads bounded -> no spills at the
// allocator's 128-reg target. hc shuffles for bb+1 issued before bb's FMAs
// (software pipeline over the ds_swizzle latency).
__global__ __launch_bounds__(256, 2)
void k_sde(const float* __restrict__ ip,
           const float* __restrict__ W_f1, const float* __restrict__ W_f2,
           const float* __restrict__ b_f2, const float* __restrict__ W_f3,
           const float* __restrict__ b_f3, const float* __restrict__ W_g1,
           const float* __restrict__ W_g2, const float* __restrict__ b_g2,
           float* __restrict__ out, const float* __restrict__ ws) {
  __shared__ __align__(16) float sW2[7 * WSTRIDE + 512];  // 8 j-strips, strip p at p*WSTRIDE
  __shared__ __align__(16) float sT[32 * TSTRIDE];        // output transpose buffer
  __shared__ __align__(16) float sF1y[H], sF1t[H], sBF[H];
  __shared__ __align__(16) float sG1y[H], sG1t[H], sBG[H];
  __shared__ __align__(16) float sF3[H], sG2[H], sBf2[H];
  __shared__ uint32_t sKA[HOR], sKB[HOR];

  const int tid = threadIdx.x;
  const int q   = tid & 7;        // lane-slot within group
  const int g   = tid >> 3;       // group/row within block (0..31)
  const int r   = blockIdx.x * 32 + g;
  const int b   = r >> 12;        // batch (uniform per block: 128 blocks/batch)
  const int lq  = tid & 63;       // lane within wave

  // ---- stage weights ----
  // sW2[(j>>3)*WSTRIDE + (j&7)*64 + k] = W_f2[k][j]
  #pragma unroll
  for (int m = 0; m < 16; ++m) {
    int flat = tid + 256 * m;     // flat = k*64 + j
    sW2[((flat & 63) >> 3) * WSTRIDE + (flat & 7) * 64 + (flat >> 6)] = W_f2[flat];
  }
  if (tid < 64) {
    sF1y[tid] = W_f1[512 * H + tid];
    sF1t[tid] = W_f1[513 * H + tid];
    sG1y[tid] = W_g1[512 * H + tid];
    sG1t[tid] = W_g1[513 * H + tid];
    sF3[tid]  = W_f3[tid];
    sG2[tid]  = W_g2[tid];
    sBf2[tid] = b_f2[tid];
    sBF[tid]  = ws[b * H + tid];
    sBG[tid]  = ws[512 + b * H + tid];
  }
  if (tid >= 64 && tid < 192) {
    const uint32_t* kws = (const uint32_t*)ws;
    int t = tid - 64;
    sKA[t] = kws[1024 + t];
    sKB[t] = kws[1152 + t];
  }
  __syncthreads();

  const float bf3 = b_f3[0];
  const float bg2 = b_g2[0];
  float y = logf(ip[b]);
  float z8 = 0.0f;

  #pragma unroll 1
  for (int t = 0; t < HOR; ++t) {
    // one threefry per lane per 8 steps: lane q generates z for step t+q
    if ((t & 7) == 0) {
      int tk = t + q;
      uint32_t x0 = 0u, x1 = (uint32_t)r;
      tf2x32(sKA[tk], sKB[tk], x0, x1);
      z8 = bits_to_normal(x0 ^ x1);
    }
    float z = __shfl(z8, (lq & 56) | (t & 7));
    float tt = (float)t;

    // h1 own chunk (k = q*8+i); invariants via b128 loads
    float h1own[8];
    {
      float4 fy0 = *(const float4*)&sF1y[q * 8], fy1 = *(const float4*)&sF1y[q * 8 + 4];
      float4 ft0 = *(const float4*)&sF1t[q * 8], ft1 = *(const float4*)&sF1t[q * 8 + 4];
      float4 fb0 = *(const float4*)&sBF[q * 8],  fb1 = *(const float4*)&sBF[q * 8 + 4];
      const float fy[8] = {fy0.x,fy0.y,fy0.z,fy0.w,fy1.x,fy1.y,fy1.z,fy1.w};
      const float ft[8] = {ft0.x,ft0.y,ft0.z,ft0.w,ft1.x,ft1.y,ft1.z,ft1.w};
      const float fb[8] = {fb0.x,fb0.y,fb0.z,fb0.w,fb1.x,fb1.y,fb1.z,fb1.w};
      #pragma unroll
      for (int i = 0; i < 8; ++i)
        h1own[i] = siluf(fmaf(y, fy[i], fmaf(tt, ft[i], fb[i])));
    }

    // accumulators init = b_f2 (same accumulation order as rounds 1-6)
    float a[8];
    {
      float4 b0 = *(const float4*)&sBf2[q * 8], b1 = *(const float4*)&sBf2[q * 8 + 4];
      a[0]=b0.x; a[1]=b0.y; a[2]=b0.z; a[3]=b0.w;
      a[4]=b1.x; a[5]=b1.y; a[6]=b1.z; a[7]=b1.w;
    }

    // bb = 0 peeled: hc = own chunk; prefetch hc for bb=1
    float hc[8], hcN[8];
    #pragma unroll
    for (int i = 0; i < 8; ++i) hcN[i] = __shfl_xor(h1own[i], 1);
    {
      const float* wb = &sW2[q * WSTRIDE + (q << 3)];
      #pragma unroll
      for (int jj = 0; jj < 8; ++jj) {
        float4 w0 = *(const float4*)&wb[jj * 64];
        float4 w1 = *(const float4*)&wb[jj * 64 + 4];
        a[jj] = fmaf(h1own[0], w0.x, a[jj]);
        a[jj] = fmaf(h1own[1], w0.y, a[jj]);
        a[jj] = fmaf(h1own[2], w0.z, a[jj]);
        a[jj] = fmaf(h1own[3], w0.w, a[jj]);
        a[jj] = fmaf(h1own[4], w1.x, a[jj]);
        a[jj] = fmaf(h1own[5], w1.y, a[jj]);
        a[jj] = fmaf(h1own[6], w1.z, a[jj]);
        a[jj] = fmaf(h1own[7], w1.w, a[jj]);
      }
    }
    // bb = 1..7: REAL loop; hc(bb) was prefetched, issue hc(bb+1) first
    #pragma unroll 1
    for (int bb = 1; bb < 8; ++bb) {
      #pragma unroll
      for (int i = 0; i < 8; ++i) hc[i] = hcN[i];
      if (bb < 7) {
        #pragma unroll
        for (int i = 0; i < 8; ++i) hcN[i] = __shfl_xor(h1own[i], bb + 1);
      }
      const float* wb = &sW2[q * WSTRIDE + ((q ^ bb) << 3)];
      #pragma unroll
      for (int jj = 0; jj < 8; ++jj) {
        float4 w0 = *(const float4*)&wb[jj * 64];
        float4 w1 = *(const float4*)&wb[jj * 64 + 4];
        a[jj] = fmaf(hc[0], w0.x, a[jj]);
        a[jj] = fmaf(hc[1], w0.y, a[jj]);
        a[jj] = fmaf(hc[2], w0.z, a[jj]);
        a[jj] = fmaf(hc[3], w0.w, a[jj]);
        a[jj] = fmaf(hc[4], w1.x, a[jj]);
        a[jj] = fmaf(hc[5], w1.y, a[jj]);
        a[jj] = fmaf(hc[6], w1.z, a[jj]);
        a[jj] = fmaf(hc[7], w1.w, a[jj]);
      }
    }

    // f-head
    float facc = 0.0f;
    {
      float4 f30 = *(const float4*)&sF3[q * 8], f31 = *(const float4*)&sF3[q * 8 + 4];
      const float f3[8] = {f30.x,f30.y,f30.z,f30.w,f31.x,f31.y,f31.z,f31.w};
      #pragma unroll
      for (int jj = 0; jj < 8; ++jj)
        facc = fmaf(siluf(a[jj]), f3[jj], facc);
    }
    facc += __shfl_xor(facc, 1);
    facc += __shfl_xor(facc, 2);
    facc += __shfl_xor(facc, 4);

    // g-net
    float gp = 0.0f;
    {
      float4 gy0 = *(const float4*)&sG1y[q * 8], gy1 = *(const float4*)&sG1y[q * 8 + 4];
      float4 gt0 = *(const float4*)&sG1t[q * 8], gt1 = *(const float4*)&sG1t[q * 8 + 4];
      float4 gb0 = *(const float4*)&sBG[q * 8],  gb1 = *(const float4*)&sBG[q * 8 + 4];
      float4 g20 = *(const float4*)&sG2[q * 8],  g21 = *(const float4*)&sG2[q * 8 + 4];
      const float gy[8] = {gy0.x,gy0.y,gy0.z,gy0.w,gy1.x,gy1.y,gy1.z,gy1.w};
      const float gt[8] = {gt0.x,gt0.y,gt0.z,gt0.w,gt1.x,gt1.y,gt1.z,gt1.w};
      const float gb[8] = {gb0.x,gb0.y,gb0.z,gb0.w,gb1.x,gb1.y,gb1.z,gb1.w};
      const float g2[8] = {g20.x,g20.y,g20.z,g20.w,g21.x,g21.y,g21.z,g21.w};
      #pragma unroll
      for (int i = 0; i < 8; ++i) {
        float pre = fmaf(y, gy[i], fmaf(tt, gt[i], gb[i]));
        gp = fmaf(siluf(pre), g2[i], gp);
      }
    }
    gp += __shfl_xor(gp, 1);
    gp += __shfl_xor(gp, 2);
    gp += __shfl_xor(gp, 4);
    float gg = softplusf(bg2 + gp) + 1e-6f;

    y = (y + (bf3 + facc)) + gg * z;   // dt = 1, sqrt_dt = 1
    float yl = fminf(fmaxf(y, -20.0f), 20.0f);
    float e = __expf(yl);
    if (q == (t & 7)) sT[g * TSTRIDE + t] = e;
  }
  __syncthreads();

  // coalesced block write: rows [blk*32, blk*32+32) are contiguous 16 KB
  float* ob = out + (size_t)blockIdx.x * 4096;
  #pragma unroll
  for (int w = 0; w < 4; ++w) {
    int idx = w * 1024 + tid * 4;
    int row = idx >> 7, col = idx & 127;
    *(float4*)&ob[idx] = *(const float4*)&sT[row * TSTRIDE + col];
  }
}

extern "C" void kernel_launch(void* const* d_in, const int* in_sizes, int n_in,
                              void* d_out, int out_size, void* d_ws, size_t ws_size,
                              hipStream_t stream) {
  const float* h_t   = (const float*)d_in[0];
  const float* ip    = (const float*)d_in[1];
  const float* W_f1  = (const float*)d_in[2];
  const float* b_f1  = (const float*)d_in[3];
  const float* W_f2  = (const float*)d_in[4];
  const float* b_f2  = (const float*)d_in[5];
  const float* W_f3  = (const float*)d_in[6];
  const float* b_f3  = (const float*)d_in[7];
  const float* W_g1  = (const float*)d_in[8];
  const float* b_g1  = (const float*)d_in[9];
  const float* W_g2  = (const float*)d_in[10];
  const float* b_g2  = (const float*)d_in[11];
  const float* W_mu  = (const float*)d_in[12];
  const float* b_mu  = (const float*)d_in[13];
  const float* W_sig = (const float*)d_in[14];
  const float* b_sig = (const float*)d_in[15];
  float* out = (float*)d_out;
  float* ws  = (float*)d_ws;

  hipLaunchKernelGGL(k_pre, dim3(9), dim3(64), 0, stream,
                     h_t, W_f1, b_f1, W_g1, b_g1, W_mu, b_mu, W_sig, b_sig, out, ws);
  hipLaunchKernelGGL(k_sde, dim3(BN / 32), dim3(256), 0, stream,
                     ip, W_f1, W_f2, b_f2, W_f3, b_f3, W_g1, W_g2, b_g2, out, ws);
}

// Round 8
// 932.067 us; speedup vs baseline: 1.3816x; 1.3816x over previous
//
#include <hip/hip_runtime.h>
#include <stdint.h>

#define HOR 128
#define NPATH 4096
#define BATCH 8
#define DM 512
#define H 64
#define BN (BATCH*NPATH)
#define WSTRIDE 516   // j-strip stride in LDS: strip bases hit disjoint bank quads
#define TSTRIDE 132   // padded transpose-row stride

// ---------------- threefry2x32 (JAX-exact) ----------------
__device__ __forceinline__ uint32_t rotl32(uint32_t x, int r) {
  return (x << r) | (x >> (32 - r));
}

__device__ __forceinline__ void tf2x32(uint32_t k0, uint32_t k1,
                                       uint32_t& x0, uint32_t& x1) {
  uint32_t k2 = k0 ^ k1 ^ 0x1BD11BDAu;
  x0 += k0; x1 += k1;
#define TFR4(a,b,c,d) \
  x0 += x1; x1 = rotl32(x1,a); x1 ^= x0; \
  x0 += x1; x1 = rotl32(x1,b); x1 ^= x0; \
  x0 += x1; x1 = rotl32(x1,c); x1 ^= x0; \
  x0 += x1; x1 = rotl32(x1,d); x1 ^= x0;
  TFR4(13,15,26,6)  x0 += k1; x1 += k2 + 1u;
  TFR4(17,29,16,24) x0 += k2; x1 += k0 + 2u;
  TFR4(13,15,26,6)  x0 += k0; x1 += k1 + 3u;
  TFR4(17,29,16,24) x0 += k1; x1 += k2 + 4u;
  TFR4(13,15,26,6)  x0 += k2; x1 += k0 + 5u;
#undef TFR4
}

// ---------------- math helpers ----------------
__device__ __forceinline__ float rcpf(float x) { return __builtin_amdgcn_rcpf(x); }
__device__ __forceinline__ float siluf(float x) {
  return x * rcpf(1.0f + __expf(-x));
}
__device__ __forceinline__ float softplusf(float x) {
  return fmaxf(x, 0.0f) + log1pf(__expf(-fabsf(x)));
}

// DPP cross-lane (VALU pipe — keeps the DS pipe free for W b128 reads).
// quad_perm xor1=0xB1, xor2=0x4E, xor3=0x1B; row_half_mirror (xor7 in 8)=0x141.
template <int C>
__device__ __forceinline__ float dppf(float x) {
  return __int_as_float(__builtin_amdgcn_update_dpp(
      0, __float_as_int(x), C, 0xF, 0xF, true));
}
// 8-lane group all-reduce; stage3 via half_mirror is bit-identical to xor4
// (quad sums are quad-uniform after stages 1-2).
__device__ __forceinline__ float red8(float v) {
  v += dppf<0xB1>(v);
  v += dppf<0x4E>(v);
  v += dppf<0x141>(v);
  return v;
}

__device__ __forceinline__ float bits_to_normal(uint32_t bits) {
  uint32_t fb = (bits >> 9) | 0x3F800000u;
  float f = __uint_as_float(fb) - 1.0f;
  float u = fmaf(f, 2.0f, -0.99999994f);
  u = fmaxf(u, -0.99999994f);
  float w = -log1pf(-u * u);
  float p;
  if (w < 5.0f) {
    w = w - 2.5f;
    p = 2.81022636e-08f;
    p = fmaf(p, w, 3.43273939e-07f);
    p = fmaf(p, w, -3.5233877e-06f);
    p = fmaf(p, w, -4.39150654e-06f);
    p = fmaf(p, w, 0.00021858087f);
    p = fmaf(p, w, -0.00125372503f);
    p = fmaf(p, w, -0.00417768164f);
    p = fmaf(p, w, 0.246640727f);
    p = fmaf(p, w, 1.50140941f);
  } else {
    w = sqrtf(w) - 3.0f;
    p = -0.000200214257f;
    p = fmaf(p, w, 0.000100950558f);
    p = fmaf(p, w, 0.00134934322f);
    p = fmaf(p, w, -0.00367342844f);
    p = fmaf(p, w, 0.00573950773f);
    p = fmaf(p, w, -0.0076224613f);
    p = fmaf(p, w, 0.00943887047f);
    p = fmaf(p, w, 1.00167406f);
    p = fmaf(p, w, 2.83297682f);
  }
  return 1.41421356237f * (p * u);
}

// ws layout (floats): [0,512) base_f1[b][j], [512,1024) base_g1[b][j],
// (u32 view) [1024,1152) keyA[t], [1152,1280) keyB[t]

__global__ void k_pre(const float* __restrict__ h_t,
                      const float* __restrict__ W_f1, const float* __restrict__ b_f1,
                      const float* __restrict__ W_g1, const float* __restrict__ b_g1,
                      const float* __restrict__ W_mu, const float* __restrict__ b_mu,
                      const float* __restrict__ W_sig, const float* __restrict__ b_sig,
                      float* __restrict__ out, float* __restrict__ ws) {
  int j = threadIdx.x;           // 0..63
  int b = blockIdx.x;
  if (b == 8) {
    uint32_t* keyA = (uint32_t*)ws + 1024;
    uint32_t* keyB = (uint32_t*)ws + 1152;
    for (int t = j; t < HOR; t += 64) {
      uint32_t x0 = 0u, x1 = (uint32_t)t;
      tf2x32(0u, 42u, x0, x1);
      keyA[t] = x0; keyB[t] = x1;
    }
    return;
  }
  const float* h = h_t + b * DM;
  float accF = b_f1[j], accG = b_g1[j];
  float pm = 0.0f, ps = 0.0f;
  #pragma unroll 4
  for (int d = 0; d < DM; ++d) {
    float hv = h[d];
    accF = fmaf(hv, W_f1[d * H + j], accF);
    accG = fmaf(hv, W_g1[d * H + j], accG);
  }
  ws[b * H + j] = accF;
  ws[512 + b * H + j] = accG;
  for (int d = j; d < DM; d += 64) {
    pm = fmaf(h[d], W_mu[d], pm);
    ps = fmaf(h[d], W_sig[d], ps);
  }
  #pragma unroll
  for (int off = 32; off > 0; off >>= 1) {
    pm += __shfl_down(pm, off);
    ps += __shfl_down(ps, off);
  }
  if (j == 0) {
    out[BN * HOR + b] = pm + b_mu[0];
    out[BN * HOR + 8 + b] = softplusf(ps + b_sig[0]) + 1e-6f;
  }
}

// 8 lanes per row; 32 rows per 256-thread block; 1024 blocks = 4096 waves =
// 4 waves/SIMD. Cross-lane h1 exchange via Gray-code DPP walk (flip 1,2,1,
// 4,1,2,1 -> chunks q^{0,1,3,2,6,7,5,4}) on the VALU pipe — R7 showed the
// ds_swizzle shuffles contend with the irreducible 128 W-b128 reads on the
// DS pipe. sched_barrier(0) after each section caps in-flight loads (the
// R2-R5 spill mechanism was cross-section load hoisting).
__global__ __launch_bounds__(256, 2)
void k_sde(const float* __restrict__ ip,
           const float* __restrict__ W_f1, const float* __restrict__ W_f2,
           const float* __restrict__ b_f2, const float* __restrict__ W_f3,
           const float* __restrict__ b_f3, const float* __restrict__ W_g1,
           const float* __restrict__ W_g2, const float* __restrict__ b_g2,
           float* __restrict__ out, const float* __restrict__ ws) {
  __shared__ __align__(16) float sW2[7 * WSTRIDE + 512];  // 8 j-strips, strip p at p*WSTRIDE
  __shared__ __align__(16) float sT[32 * TSTRIDE];        // output transpose buffer
  __shared__ __align__(16) float sF1y[H], sF1t[H], sBF[H];
  __shared__ __align__(16) float sG1y[H], sG1t[H], sBG[H];
  __shared__ __align__(16) float sF3[H], sG2[H], sBf2[H];
  __shared__ uint32_t sKA[HOR], sKB[HOR];

  const int tid = threadIdx.x;
  const int q   = tid & 7;        // lane-slot within group
  const int g   = tid >> 3;       // group/row within block (0..31)
  const int r   = blockIdx.x * 32 + g;
  const int b   = r >> 12;        // batch (uniform per block: 128 blocks/batch)
  const int lq  = tid & 63;       // lane within wave

  // ---- stage weights ----
  // sW2[(j>>3)*WSTRIDE + (j&7)*64 + k] = W_f2[k][j]
  #pragma unroll
  for (int m = 0; m < 16; ++m) {
    int flat = tid + 256 * m;     // flat = k*64 + j
    sW2[((flat & 63) >> 3) * WSTRIDE + (flat & 7) * 64 + (flat >> 6)] = W_f2[flat];
  }
  if (tid < 64) {
    sF1y[tid] = W_f1[512 * H + tid];
    sF1t[tid] = W_f1[513 * H + tid];
    sG1y[tid] = W_g1[512 * H + tid];
    sG1t[tid] = W_g1[513 * H + tid];
    sF3[tid]  = W_f3[tid];
    sG2[tid]  = W_g2[tid];
    sBf2[tid] = b_f2[tid];
    sBF[tid]  = ws[b * H + tid];
    sBG[tid]  = ws[512 + b * H + tid];
  }
  if (tid >= 64 && tid < 192) {
    const uint32_t* kws = (const uint32_t*)ws;
    int t = tid - 64;
    sKA[t] = kws[1024 + t];
    sKB[t] = kws[1152 + t];
  }
  __syncthreads();

  const float bf3 = b_f3[0];
  const float bg2 = b_g2[0];
  float y = logf(ip[b]);
  float z8 = 0.0f;

  #pragma unroll 1
  for (int t = 0; t < HOR; ++t) {
    // one threefry per lane per 8 steps: lane q generates z for step t+q
    if ((t & 7) == 0) {
      int tk = t + q;
      uint32_t x0 = 0u, x1 = (uint32_t)r;
      tf2x32(sKA[tk], sKB[tk], x0, x1);
      z8 = bits_to_normal(x0 ^ x1);
    }
    float z = __shfl(z8, (lq & 56) | (t & 7));
    float tt = (float)t;

    // h1 own chunk (k = q*8+i); invariants via b128 loads
    float h[8];
    {
      float4 fy0 = *(const float4*)&sF1y[q * 8], fy1 = *(const float4*)&sF1y[q * 8 + 4];
      float4 ft0 = *(const float4*)&sF1t[q * 8], ft1 = *(const float4*)&sF1t[q * 8 + 4];
      float4 fb0 = *(const float4*)&sBF[q * 8],  fb1 = *(const float4*)&sBF[q * 8 + 4];
      const float fy[8] = {fy0.x,fy0.y,fy0.z,fy0.w,fy1.x,fy1.y,fy1.z,fy1.w};
      const float ft[8] = {ft0.x,ft0.y,ft0.z,ft0.w,ft1.x,ft1.y,ft1.z,ft1.w};
      const float fb[8] = {fb0.x,fb0.y,fb0.z,fb0.w,fb1.x,fb1.y,fb1.z,fb1.w};
      #pragma unroll
      for (int i = 0; i < 8; ++i)
        h[i] = siluf(fmaf(y, fy[i], fmaf(tt, ft[i], fb[i])));
    }

    // accumulators init = b_f2
    float a[8];
    {
      float4 b0 = *(const float4*)&sBf2[q * 8], b1 = *(const float4*)&sBf2[q * 8 + 4];
      a[0]=b0.x; a[1]=b0.y; a[2]=b0.z; a[3]=b0.w;
      a[4]=b1.x; a[5]=b1.y; a[6]=b1.z; a[7]=b1.w;
    }

    // one Gray-walk section: h currently holds chunk (q ^ cum)
    auto wsec = [&](int cum) {
      const float* wb = &sW2[q * WSTRIDE + ((q ^ cum) << 3)];
      #pragma unroll
      for (int jj = 0; jj < 8; ++jj) {
        float4 w0 = *(const float4*)&wb[jj * 64];
        float4 w1 = *(const float4*)&wb[jj * 64 + 4];
        a[jj] = fmaf(h[0], w0.x, a[jj]);
        a[jj] = fmaf(h[1], w0.y, a[jj]);
        a[jj] = fmaf(h[2], w0.z, a[jj]);
        a[jj] = fmaf(h[3], w0.w, a[jj]);
        a[jj] = fmaf(h[4], w1.x, a[jj]);
        a[jj] = fmaf(h[5], w1.y, a[jj]);
        a[jj] = fmaf(h[6], w1.z, a[jj]);
        a[jj] = fmaf(h[7], w1.w, a[jj]);
      }
      __builtin_amdgcn_sched_barrier(0);
    };
    auto flip1 = [&]() {
      #pragma unroll
      for (int i = 0; i < 8; ++i) h[i] = dppf<0xB1>(h[i]);
    };
    auto flip2 = [&]() {
      #pragma unroll
      for (int i = 0; i < 8; ++i) h[i] = dppf<0x4E>(h[i]);
    };
    auto flip4 = [&]() {   // xor4 = xor7 (half_mirror) then xor3 (quad_perm)
      #pragma unroll
      for (int i = 0; i < 8; ++i) h[i] = dppf<0x1B>(dppf<0x141>(h[i]));
    };

    wsec(0);
    flip1(); wsec(1);
    flip2(); wsec(3);
    flip1(); wsec(2);
    flip4(); wsec(6);
    flip1(); wsec(7);
    flip2(); wsec(5);
    flip1(); wsec(4);

    // f-head
    float facc = 0.0f;
    {
      float4 f30 = *(const float4*)&sF3[q * 8], f31 = *(const float4*)&sF3[q * 8 + 4];
      const float f3[8] = {f30.x,f30.y,f30.z,f30.w,f31.x,f31.y,f31.z,f31.w};
      #pragma unroll
      for (int jj = 0; jj < 8; ++jj)
        facc = fmaf(siluf(a[jj]), f3[jj], facc);
    }
    facc = red8(facc);

    // g-net
    float gp = 0.0f;
    {
      float4 gy0 = *(const float4*)&sG1y[q * 8], gy1 = *(const float4*)&sG1y[q * 8 + 4];
      float4 gt0 = *(const float4*)&sG1t[q * 8], gt1 = *(const float4*)&sG1t[q * 8 + 4];
      float4 gb0 = *(const float4*)&sBG[q * 8],  gb1 = *(const float4*)&sBG[q * 8 + 4];
      float4 g20 = *(const float4*)&sG2[q * 8],  g21 = *(const float4*)&sG2[q * 8 + 4];
      const float gy[8] = {gy0.x,gy0.y,gy0.z,gy0.w,gy1.x,gy1.y,gy1.z,gy1.w};
      const float gt[8] = {gt0.x,gt0.y,gt0.z,gt0.w,gt1.x,gt1.y,gt1.z,gt1.w};
      const float gb[8] = {gb0.x,gb0.y,gb0.z,gb0.w,gb1.x,gb1.y,gb1.z,gb1.w};
      const float g2[8] = {g20.x,g20.y,g20.z,g20.w,g21.x,g21.y,g21.z,g21.w};
      #pragma unroll
      for (int i = 0; i < 8; ++i) {
        float pre = fmaf(y, gy[i], fmaf(tt, gt[i], gb[i]));
        gp = fmaf(siluf(pre), g2[i], gp);
      }
    }
    gp = red8(gp);
    float gg = softplusf(bg2 + gp) + 1e-6f;

    y = (y + (bf3 + facc)) + gg * z;   // dt = 1, sqrt_dt = 1
    float yl = fminf(fmaxf(y, -20.0f), 20.0f);
    float e = __expf(yl);
    if (q == (t & 7)) sT[g * TSTRIDE + t] = e;
  }
  __syncthreads();

  // coalesced block write: rows [blk*32, blk*32+32) are contiguous 16 KB
  float* ob = out + (size_t)blockIdx.x * 4096;
  #pragma unroll
  for (int w = 0; w < 4; ++w) {
    int idx = w * 1024 + tid * 4;
    int row = idx >> 7, col = idx & 127;
    *(float4*)&ob[idx] = *(const float4*)&sT[row * TSTRIDE + col];
  }
}

extern "C" void kernel_launch(void* const* d_in, const int* in_sizes, int n_in,
                              void* d_out, int out_size, void* d_ws, size_t ws_size,
                              hipStream_t stream) {
  const float* h_t   = (const float*)d_in[0];
  const float* ip    = (const float*)d_in[1];
  const float* W_f1  = (const float*)d_in[2];
  const float* b_f1  = (const float*)d_in[3];
  const float* W_f2  = (const float*)d_in[4];
  const float* b_f2  = (const float*)d_in[5];
  const float* W_f3  = (const float*)d_in[6];
  const float* b_f3  = (const float*)d_in[7];
  const float* W_g1  = (const float*)d_in[8];
  const float* b_g1  = (const float*)d_in[9];
  const float* W_g2  = (const float*)d_in[10];
  const float* b_g2  = (const float*)d_in[11];
  const float* W_mu  = (const float*)d_in[12];
  const float* b_mu  = (const float*)d_in[13];
  const float* W_sig = (const float*)d_in[14];
  const float* b_sig = (const float*)d_in[15];
  float* out = (float*)d_out;
  float* ws  = (float*)d_ws;

  hipLaunchKernelGGL(k_pre, dim3(9), dim3(64), 0, stream,
                     h_t, W_f1, b_f1, W_g1, b_g1, W_mu, b_mu, W_sig, b_sig, out, ws);
  hipLaunchKernelGGL(k_sde, dim3(BN / 32), dim3(256), 0, stream,
                     ip, W_f1, W_f2, b_f2, W_f3, b_f3, W_g1, W_g2, b_g2, out, ws);
}